// Round 10
// baseline (30.939 us; speedup 1.0000x reference)
//
#include <hip/hip_runtime.h>
#include <hip/hip_bf16.h>
#include <stdint.h>

// LogLinearCDE: out = softmax(W_out @ (y0 * prod_l flows[l]) + b_out)
// flows[l,h] = 1 + sum_c logsigs[l,c]*vf_A[c,h];  y0 = W_in@x0 + b_in
// R10: 3 kernels, no fences. (1) MFMA partial products with INLINE B
// conversion from fp32 vfA (pack kernel folded in; B depends only on col/g).
// (2) tailA: per-h chunk product + y0 + per-block partial logits.
// (3) tailB: 1 block sums partials + softmax.

#define LSTEPS 16384
#define HID    4096
#define CC     17
#define NLAB   10
#define NW     16          // packed u32 words per col (K padded to 32 bf16)
#define NCHUNK 256
#define CR     64          // rows per chunk
#define APAD   20          // LDS A row stride in words (80B, 16B-aligned)
#define HPB    16          // h per tailA block
#define RBLK   256         // tailA blocks

typedef __attribute__((ext_vector_type(8))) short short8;
typedef __attribute__((ext_vector_type(4))) float f32x4;
typedef __attribute__((ext_vector_type(4))) uint32_t u32x4;

static __device__ __forceinline__ unsigned short f2bf(float x) {
  __hip_bfloat16 h = __float2bfloat16(x);
  return *reinterpret_cast<unsigned short*>(&h);
}
static __device__ __forceinline__ float bf2f(unsigned short u) {
  __hip_bfloat16 h; *reinterpret_cast<unsigned short*>(&h) = u;
  return __bfloat162float(h);
}
static __device__ __forceinline__ uint32_t pack_hi(float v0, float v1) {
  return (uint32_t)f2bf(v0) | ((uint32_t)f2bf(v1) << 16);
}
static __device__ __forceinline__ uint32_t pack_lo(float v0, float v1) {
  float r0 = v0 - bf2f(f2bf(v0)), r1 = v1 - bf2f(f2bf(v1));
  return (uint32_t)f2bf(r0) | ((uint32_t)f2bf(r1) << 16);
}

// partial products over 64-row chunks via MFMA; B packed inline from fp32.
__global__ __launch_bounds__(256, 4) void partial_mfma_kernel(
    const float* __restrict__ logsigs, const float* __restrict__ vfA,
    float* __restrict__ ws_p) {
  const int hb = blockIdx.x;        // 0..3 (1024 cols each)
  const int chunk = blockIdx.y;     // 0..255
  const int tid = threadIdx.x;

  __shared__ __align__(16) uint32_t sAh[CR][APAD], sAl[CR][APAD];

  // convert this chunk's logsig rows (64 x 17) to packed bf16 hi/lo words
  const float* __restrict__ src = logsigs + (size_t)chunk*CR*CC;
  for (int e = tid; e < CR*NW; e += 256) {
    const int r = e >> 4, j = e & (NW-1);
    const int k0 = 2*j, k1 = k0 + 1;
    const float v0 = (k0 < CC) ? src[r*CC + k0] : 0.0f;
    const float v1 = (k1 < CC) ? src[r*CC + k1] : 0.0f;
    sAh[r][j] = pack_hi(v0, v1);
    sAl[r][j] = pack_lo(v0, v1);
  }
  __syncthreads();

  const int wv = tid >> 6, lane = tid & 63;
  const int g = lane >> 4, cr = lane & 15;

  short8 Ah[4], Al[4];
  #pragma unroll
  for (int mt = 0; mt < 4; ++mt) {
    const int r = mt*16 + cr;
    Ah[mt] = *reinterpret_cast<const short8*>(&sAh[r][4*g]);
    Al[mt] = *reinterpret_cast<const short8*>(&sAl[r][4*g]);
  }

  const int cbase = hb*1024 + wv*256;
  const int kbase = 8*g;
  #pragma unroll 2
  for (int nt = 0; nt < 16; ++nt) {
    const int c = cbase + nt*16 + cr;
    // inline B conversion: 8 fp32 (k = kbase..kbase+7) -> bf16 hi/lo fragments
    float vb[8];
    #pragma unroll
    for (int k = 0; k < 8; ++k) {
      const int kk = kbase + k;
      vb[k] = (kk < CC) ? vfA[(size_t)kk*HID + c] : 0.0f;
    }
    u32x4 bh, bl;
    #pragma unroll
    for (int j = 0; j < 4; ++j) {
      bh[j] = pack_hi(vb[2*j], vb[2*j+1]);
      bl[j] = pack_lo(vb[2*j], vb[2*j+1]);
    }
    const short8 Bh = __builtin_bit_cast(short8, bh);
    const short8 Bl = __builtin_bit_cast(short8, bl);

    float pcol = 1.0f;
    #pragma unroll
    for (int mt = 0; mt < 4; ++mt) {
      f32x4 acc = {0.0f, 0.0f, 0.0f, 0.0f};
      acc = __builtin_amdgcn_mfma_f32_16x16x32_bf16(Ah[mt], Bh, acc, 0, 0, 0);
      acc = __builtin_amdgcn_mfma_f32_16x16x32_bf16(Ah[mt], Bl, acc, 0, 0, 0);
      acc = __builtin_amdgcn_mfma_f32_16x16x32_bf16(Al[mt], Bh, acc, 0, 0, 0);
      pcol *= (1.0f + acc[0]) * (1.0f + acc[1]) * (1.0f + acc[2]) * (1.0f + acc[3]);
    }
    pcol *= __shfl_xor(pcol, 16, 64);
    pcol *= __shfl_xor(pcol, 32, 64);
    if (g == 0) ws_p[(size_t)chunk*HID + c] = pcol;
  }
}

// tailA: per-h product over all chunks, y0, per-block partial logits.
__global__ __launch_bounds__(256) void tailA_kernel(
    const float* __restrict__ ws_p, const float* __restrict__ Win,
    const float* __restrict__ bin,  const float* __restrict__ x0,
    const float* __restrict__ Wout, float* __restrict__ ws_lp) {
  const int b = blockIdx.x, tid = threadIdx.x;
  const int h0 = b * HPB;
  const int hh = tid & 15, sl = tid >> 4;

  __shared__ float sp[HPB][17];
  __shared__ float sy[HPB];

  // slice product: thread (hh,sl) multiplies chunks sl*16..sl*16+15 for h0+hh
  {
    float p = 1.0f;
    #pragma unroll
    for (int i = 0; i < 16; ++i)
      p *= ws_p[(size_t)(sl*16 + i)*HID + h0 + hh];
    sp[hh][sl] = p;
  }
  __syncthreads();

  if (tid < HPB) {
    float P = 1.0f;
    #pragma unroll
    for (int s = 0; s < 16; ++s) P *= sp[tid][s];
    const int h = h0 + tid;
    const float4* __restrict__ wrow = reinterpret_cast<const float4*>(Win + (size_t)h*16);
    float y = bin[h];
    #pragma unroll
    for (int q = 0; q < 4; ++q) {
      float4 w = wrow[q];
      y = fmaf(w.x, x0[q*4+0], y);
      y = fmaf(w.y, x0[q*4+1], y);
      y = fmaf(w.z, x0[q*4+2], y);
      y = fmaf(w.w, x0[q*4+3], y);
    }
    sy[tid] = y * P;
  }
  __syncthreads();

  // partial logits for this block's 16 h (fixed shfl order -> deterministic)
  if (tid < NLAB*HPB) {                     // 160 threads
    const int j = tid >> 4, k = tid & 15;
    float v = Wout[(size_t)j*HID + h0 + k] * sy[k];
    v += __shfl_xor(v, 1, 64);
    v += __shfl_xor(v, 2, 64);
    v += __shfl_xor(v, 4, 64);
    v += __shfl_xor(v, 8, 64);
    if (k == 0) ws_lp[b*16 + j] = v;
  }
}

// tailB: one block sums 256x10 partial logits (deterministic order) + softmax
__global__ __launch_bounds__(256) void tailB_kernel(
    const float* __restrict__ ws_lp, const float* __restrict__ bout,
    float* __restrict__ out) {
  const int tid = threadIdx.x;
  __shared__ float slog[NLAB];

  if (tid < NLAB*16) {                      // j x 16 block-slices
    const int j = tid >> 4, s = tid & 15;
    float acc = 0.0f;
    #pragma unroll
    for (int bb = 0; bb < 16; ++bb)
      acc += ws_lp[(s*16 + bb)*16 + j];
    acc += __shfl_xor(acc, 1, 64);
    acc += __shfl_xor(acc, 2, 64);
    acc += __shfl_xor(acc, 4, 64);
    acc += __shfl_xor(acc, 8, 64);
    if (s == 0) slog[j] = acc + bout[j];
  }
  __syncthreads();
  if (tid == 0) {
    float m = slog[0];
    #pragma unroll
    for (int j = 1; j < NLAB; ++j) m = fmaxf(m, slog[j]);
    float ssum = 0.0f;
    float e[NLAB];
    #pragma unroll
    for (int j = 0; j < NLAB; ++j) { e[j] = __expf(slog[j] - m); ssum += e[j]; }
    const float inv = 1.0f / ssum;
    #pragma unroll
    for (int j = 0; j < NLAB; ++j) out[j] = e[j] * inv;
  }
}

extern "C" void kernel_launch(void* const* d_in, const int* in_sizes, int n_in,
                              void* d_out, int out_size, void* d_ws, size_t ws_size,
                              hipStream_t stream) {
  // inputs: 0=ts (unused), 1=logsigs (L,C), 2=x0 (D), 3=W_in (H,D), 4=b_in (H),
  //         5=vf_A (C,H), 6=W_out (10,H), 7=b_out (10)
  const float* logsigs = (const float*)d_in[1];
  const float* x0      = (const float*)d_in[2];
  const float* Win     = (const float*)d_in[3];
  const float* bin     = (const float*)d_in[4];
  const float* vfA     = (const float*)d_in[5];
  const float* Wout    = (const float*)d_in[6];
  const float* bout    = (const float*)d_in[7];
  float* out = (float*)d_out;

  // workspace layout (16B-aligned slices)
  float* ws_p  = (float*)d_ws;                         // 256*4096 f32 = 4MB
  float* ws_lp = ws_p + (size_t)NCHUNK*HID;            // RBLK*16 f32

  partial_mfma_kernel<<<dim3(4, NCHUNK), 256, 0, stream>>>(logsigs, vfA, ws_p);
  tailA_kernel<<<RBLK, 256, 0, stream>>>(ws_p, Win, bin, x0, Wout, ws_lp);
  tailB_kernel<<<1, 256, 0, stream>>>(ws_lp, bout, out);
}